// Round 4
// baseline (90.292 us; speedup 1.0000x reference)
//
#include <hip/hip_runtime.h>

// FUME epipolar translation, fp32 in/out. B from in_sizes[3]; C,H,W = 4,128,128.
//
// R15: MEASUREMENT ROUND. R14 structure (octet-per-pixel, transposed [u][k]
// cube) with the k-loop wrapped in REP=9 asm-fenced repetitions so fume_kernel
// rises above the ~40us ws-poison fills in the rocprof top-5 and we finally get
// its real counters (VALUBusy / Occupancy / FETCH / VGPR). The last repetition
// recomputes the identical accumulation from zeros -> results bit-identical to
// R14 (absmax 0.0625). T_main = row_dur / 9. dur_us this round is sacrificial.
//
// History: R11 67.2 (8 seg-waves x 64 px, k-major cube) | R12 +pad neutral ->
// channel-alias theory dead | R13 wave-per-pixel 79.3 regressed | R14 octet
// 69.6 neutral -> line-transaction theory dead. Pure VALU issue model ~1-2us.
// Surviving theory: VMEM-latency-bound at high occupancy -> expect VALUBusy
// 10-25%, Occupancy ~high, FETCH ~0 (cubes L3-resident, FETCH counts HBM only).
//
// Workspace (16B entries = {half2(tap0,tap1)}ch=0..3), row stride LDK=128:
//   horiz cube at entry ofs b*32768:        entry[u][s] = {img[ch][u][s], img[ch][u+1][s]}
//   vert  cube at entry ofs b*32768+16384:  entry[u][k] = {img[ch][k][u], img[ch][k][u+1]}
// (second tap clamped at the image edge; row u=127 is never read: i0<=126.)

#define CC 4
#define HH 128
#define WW 128
#define LDK 128              /* cube row stride, entries (16B each) */
#define CUBE (128 * LDK)     /* one direction cube, entries */
#define REP 9                /* measurement multiplier for the k-loop */

typedef _Float16 h2 __attribute__((ext_vector_type(2)));

__global__ void __launch_bounds__(256) fume_stage(
        const float* __restrict__ img, float4* __restrict__ ws) {
    __shared__ float tile[4][17][17];
    int x0 = blockIdx.x * 16, y0 = blockIdx.y * 16, b = blockIdx.z;
    int tx = threadIdx.x, ty = threadIdx.y;   // 16x16
    int id = ty * 16 + tx;
    const float* src = img + (size_t)b * CC * HH * WW;

    #pragma unroll
    for (int ch = 0; ch < 4; ++ch) {
        #pragma unroll
        for (int e = 0; e < 2; ++e) {
            int idx = id + e * 256;
            if (idx < 289) {
                int i = idx / 17, j = idx % 17;
                int r = min(y0 + i, HH - 1);
                int c = min(x0 + j, WW - 1);
                tile[ch][i][j] = src[(ch * HH + r) * WW + c];
            }
        }
    }
    __syncthreads();

    float4* base_h = ws + (size_t)b * (2 * CUBE);
    float4* base_v = base_h + CUBE;

    // horiz (transposed): entry[u = y0+ty][s = x0+tx] = {img[u][s], img[u+1][s]}
    {
        h2 p0 = { (_Float16)tile[0][ty][tx], (_Float16)tile[0][ty + 1][tx] };
        h2 p1 = { (_Float16)tile[1][ty][tx], (_Float16)tile[1][ty + 1][tx] };
        h2 p2 = { (_Float16)tile[2][ty][tx], (_Float16)tile[2][ty + 1][tx] };
        h2 p3 = { (_Float16)tile[3][ty][tx], (_Float16)tile[3][ty + 1][tx] };
        float4 e = make_float4(__builtin_bit_cast(float, p0),
                               __builtin_bit_cast(float, p1),
                               __builtin_bit_cast(float, p2),
                               __builtin_bit_cast(float, p3));
        base_h[(y0 + ty) * LDK + (x0 + tx)] = e;
    }
    // vert (transposed): entry[u = x0+ty][k = y0+tx] = {img[k][u], img[k][u+1]}
    {
        h2 p0 = { (_Float16)tile[0][tx][ty], (_Float16)tile[0][tx][ty + 1] };
        h2 p1 = { (_Float16)tile[1][tx][ty], (_Float16)tile[1][tx][ty + 1] };
        h2 p2 = { (_Float16)tile[2][tx][ty], (_Float16)tile[2][tx][ty + 1] };
        h2 p3 = { (_Float16)tile[3][tx][ty], (_Float16)tile[3][tx][ty + 1] };
        float4 e = make_float4(__builtin_bit_cast(float, p0),
                               __builtin_bit_cast(float, p1),
                               __builtin_bit_cast(float, p2),
                               __builtin_bit_cast(float, p3));
        base_v[(x0 + ty) * LDK + (y0 + tx)] = e;
    }
}

__global__ void __launch_bounds__(512) fume_kernel(
        const float4* __restrict__ cubes,
        const float* __restrict__ F,
        const float* __restrict__ dsf,
        float* __restrict__ out) {
    int lane = threadIdx.x;              // 0..63
    int sub  = lane & 7;                 // k-offset within octet
    int oct  = lane >> 3;                // pixel within wave (0..7)
    int w    = threadIdx.y;              // wave id (0..7)
    int x = blockIdx.x * 64 + w * 8 + oct;
    int y = blockIdx.y;
    int b = blockIdx.z;

    float d = dsf[b];
    float F00 = F[0], F01 = F[1], F02 = F[2];
    float F10 = F[3], F11 = F[4], F12 = F[5];
    float F20 = F[6], F21 = F[7], F22 = F[8];

    // Exact reference op order (no fma contraction). Per-pixel (octet-uniform).
    float px = __fmul_rn((float)x, d);
    float py = __fmul_rn((float)y, d);
    float av = __fadd_rn(__fadd_rn(__fmul_rn(F00, px), __fmul_rn(F01, py)), F02);
    float bv = __fadd_rn(__fadd_rn(__fmul_rn(F10, px), __fmul_rn(F11, py)), F12);
    float cv = __fadd_rn(__fadd_rn(__fmul_rn(F20, px), __fmul_rn(F21, py)), F22);

    bool horiz  = fabsf(bv) >= fabsf(av);
    float ncoef = horiz ? av : bv;
    float den   = __fmul_rn(horiz ? bv : av, d);
    float nrec  = -__fdiv_rn(1.0f, den);   // den 0/Inf/NaN -> u NaN -> masked

    const float4* P = cubes + (size_t)b * (2 * CUBE) + (horiz ? 0 : CUBE);

    // Conservative valid-k interval (octet-uniform; exact mask still applied).
    float A  = __fmul_rn(__fmul_rn(ncoef, d), nrec);
    float Bc = __fmul_rn(cv, nrec);
    int lkmin, lkmax;
    if (fabsf(A) > 1e-20f) {
        float inv = 1.0f / A;
        float k1 = (0.0f   - Bc) * inv;
        float k2 = (127.0f - Bc) * inv;
        float lo = fmaxf(fminf(k1, k2) - 2.0f, 0.0f);
        float hi = fminf(fmaxf(k1, k2) + 2.0f, 127.0f);
        if (lo > hi || !(lo == lo)) { lkmin = 1; lkmax = 0; }
        else { lkmin = (int)lo; lkmax = (int)hi; }
    } else {
        bool full = (Bc >= 0.0f) && (Bc <= 127.0f);
        lkmin = full ? 0 : 1;
        lkmax = full ? 127 : 0;
    }

    // Wave-uniform trip count = max over the 8 octets of ceil(len/8).
    int len = lkmax - lkmin + 1;          // may be <=0 (empty)
    int cnt = (len + 7) >> 3;
    int wm  = cnt;
    #pragma unroll
    for (int m = 1; m < 64; m <<= 1) wm = max(wm, __shfl_xor(wm, m));

    float a0 = 0.f, a1 = 0.f, a2 = 0.f, a3 = 0.f;
    // MEASUREMENT: repeat the k-loop REP times behind asm fences. Reps 0..REP-2
    // are discarded (re-zeroed) but cannot be DCE'd/hoisted; the final rep
    // computes exactly the R14 result from zeros -> output bit-identical.
    for (int rep = 0; rep < REP; ++rep) {
        a0 = 0.f; a1 = 0.f; a2 = 0.f; a3 = 0.f;
        asm volatile("" : "+v"(a0), "+v"(a1), "+v"(a2), "+v"(a3));
        for (int s = 0; s < wm; ++s) {
            int k = lkmin + (s << 3) + sub;   // octet covers 8 consecutive k
            if (k <= lkmax) {
                float m  = __fmul_rn((float)k, d);
                float q  = __fadd_rn(__fmul_rn(ncoef, m), cv);
                float u  = __fmul_rn(q, nrec);
                bool ok  = (u >= 0.f) && (u <= 127.f);
                int i0   = (int)floorf(u);    // NaN->0, sat; clamped next
                i0 = max(0, min(i0, 126));
                float wq = __fsub_rn(u, (float)i0);   // ==1 at u==127 -> row[127]
                h2 wp = __builtin_bit_cast(h2,
                            __builtin_amdgcn_cvt_pkrtz(__fsub_rn(1.f, wq), wq));
                wp = ok ? wp : (h2){(_Float16)0.f, (_Float16)0.f};
                float4 e = P[i0 * LDK + k];   // [u][k]: consecutive k contiguous
                a0 = __builtin_amdgcn_fdot2(wp, __builtin_bit_cast(h2, e.x), a0, false);
                a1 = __builtin_amdgcn_fdot2(wp, __builtin_bit_cast(h2, e.y), a1, false);
                a2 = __builtin_amdgcn_fdot2(wp, __builtin_bit_cast(h2, e.z), a2, false);
                a3 = __builtin_amdgcn_fdot2(wp, __builtin_bit_cast(h2, e.w), a3, false);
            }
        }
        asm volatile("" : "+v"(a0), "+v"(a1), "+v"(a2), "+v"(a3));
    }

    // Octet tree-reduction over the 8 k-slots (deterministic order, no LDS).
    #pragma unroll
    for (int m = 1; m < 8; m <<= 1) {
        a0 = __fadd_rn(a0, __shfl_xor(a0, m));
        a1 = __fadd_rn(a1, __shfl_xor(a1, m));
        a2 = __fadd_rn(a2, __shfl_xor(a2, m));
        a3 = __fadd_rn(a3, __shfl_xor(a3, m));
    }

    if (sub < 4) {                        // lanes 0..3 of each octet: one ch each
        float v = (sub == 0) ? a0 : (sub == 1) ? a1 : (sub == 2) ? a2 : a3;
        out[(((size_t)b * CC + sub) * HH + y) * WW + x] = v;
    }
}

extern "C" void kernel_launch(void* const* d_in, const int* in_sizes, int n_in,
                              void* d_out, int out_size, void* d_ws, size_t ws_size,
                              hipStream_t stream) {
    const float* view1 = (const float*)d_in[0];
    const float* F21   = (const float*)d_in[1];
    const float* dsf   = (const float*)d_in[3];

    const int B = in_sizes[3];

    dim3 stb(16, 16, 1);
    dim3 stg(WW / 16, HH / 16, B);
    fume_stage<<<stg, stb, 0, stream>>>(view1, (float4*)d_ws);

    dim3 ftb(64, 8, 1);
    dim3 ftg(WW / 64, HH, B);
    fume_kernel<<<ftg, ftb, 0, stream>>>((const float4*)d_ws, F21, dsf,
                                         (float*)d_out);
}

// Round 5
// 69.690 us; speedup vs baseline: 1.2956x; 1.2956x over previous
//
#include <hip/hip_runtime.h>

// FUME epipolar translation, fp32 in/out. B from in_sizes[3]; C,H,W = 4,128,128.
//
// R16: stage-v3 (no-LDS, row-mapped, 1024 blocks) + R11 main on transposed cube.
//  Budget from R15's REP=9 probe: k-loop = 2.6us of a 67us total; fill = 40us
//  (harness re-poison, fixed); so the controllable cost is stage (~5-10us,
//  256-block launch-ramp-bound) + main wave overhead (~3us) + gaps. This round
//  attacks the stage and reverts main to R11's best-measured structure.
//  - stage v3: one thread per cube entry, grid (128 u-rows, 2 dirs, B) x 128thr.
//    horiz: coalesced row reads+writes. vert: scattered column reads (only
//    ~260K line-requests chip-wide ~ 0.4us) + coalesced writes. No LDS/sync.
//    Entry values bit-identical to R13/R14/R15 stage (same clamp, same cast).
//  - main: R11's per-lane k-interval + 8-seg split + part[] reduction (best
//    measured 67.2us), body address on the transposed [u][k] cube P[i0*LDK+k]
//    (layout validated R13-R15). Output bit-identical to R11.
//
// Workspace (16B entries = {half2(tap0,tap1)}ch=0..3), row stride LDK=128:
//   horiz cube at entry ofs b*32768:        entry[u][s] = {img[ch][u][s], img[ch][u+1][s]}
//   vert  cube at entry ofs b*32768+16384:  entry[u][k] = {img[ch][k][u], img[ch][k][u+1]}
// (second tap clamped at the image edge; row u=127 is never read: i0<=126.)

#define CC 4
#define HH 128
#define WW 128
#define LDK 128              /* cube row stride, entries (16B each) */
#define CUBE (128 * LDK)     /* one direction cube, entries */

typedef _Float16 h2 __attribute__((ext_vector_type(2)));

__global__ void __launch_bounds__(128) fume_stage(
        const float* __restrict__ img, float4* __restrict__ ws) {
    int t   = threadIdx.x;               // 0..127 : entry column within the row
    int u   = blockIdx.x;                // 0..127 : cube row
    int dir = blockIdx.y;                // 0 horiz, 1 vert
    int b   = blockIdx.z;
    const float* src = img + (size_t)b * CC * HH * WW;
    float4* base = ws + (size_t)b * (2 * CUBE) + (dir ? CUBE : 0);
    int u1 = min(u + 1, HH - 1);

    h2 p0, p1, p2, p3;
    if (dir == 0) {
        // horiz: entry[u][t] = {img[ch][u][t], img[ch][u1][t]} — coalesced rows
        p0 = (h2){ (_Float16)src[(0 * HH + u) * WW + t], (_Float16)src[(0 * HH + u1) * WW + t] };
        p1 = (h2){ (_Float16)src[(1 * HH + u) * WW + t], (_Float16)src[(1 * HH + u1) * WW + t] };
        p2 = (h2){ (_Float16)src[(2 * HH + u) * WW + t], (_Float16)src[(2 * HH + u1) * WW + t] };
        p3 = (h2){ (_Float16)src[(3 * HH + u) * WW + t], (_Float16)src[(3 * HH + u1) * WW + t] };
    } else {
        // vert: entry[u][t] = {img[ch][t][u], img[ch][t][u1]} — column reads
        // (adjacent-pair taps share a line; total request count is tiny)
        p0 = (h2){ (_Float16)src[(0 * HH + t) * WW + u], (_Float16)src[(0 * HH + t) * WW + u1] };
        p1 = (h2){ (_Float16)src[(1 * HH + t) * WW + u], (_Float16)src[(1 * HH + t) * WW + u1] };
        p2 = (h2){ (_Float16)src[(2 * HH + t) * WW + u], (_Float16)src[(2 * HH + t) * WW + u1] };
        p3 = (h2){ (_Float16)src[(3 * HH + t) * WW + u], (_Float16)src[(3 * HH + t) * WW + u1] };
    }
    base[u * LDK + t] = make_float4(__builtin_bit_cast(float, p0),
                                    __builtin_bit_cast(float, p1),
                                    __builtin_bit_cast(float, p2),
                                    __builtin_bit_cast(float, p3));
}

__global__ void __launch_bounds__(512) fume_kernel(
        const float4* __restrict__ cubes,
        const float* __restrict__ F,
        const float* __restrict__ dsf,
        float* __restrict__ out) {
    int tx  = threadIdx.x;               // 0..63 : x within group (one wave)
    int seg = threadIdx.y;               // 0..7  : k-segment (wave id)
    int x = blockIdx.x * 64 + tx;
    int y = blockIdx.y;
    int b = blockIdx.z;

    float d = dsf[b];
    float F00 = F[0], F01 = F[1], F02 = F[2];
    float F10 = F[3], F11 = F[4], F12 = F[5];
    float F20 = F[6], F21 = F[7], F22 = F[8];

    // Exact reference op order (no fma contraction).
    float px = __fmul_rn((float)x, d);
    float py = __fmul_rn((float)y, d);
    float av = __fadd_rn(__fadd_rn(__fmul_rn(F00, px), __fmul_rn(F01, py)), F02);
    float bv = __fadd_rn(__fadd_rn(__fmul_rn(F10, px), __fmul_rn(F11, py)), F12);
    float cv = __fadd_rn(__fadd_rn(__fmul_rn(F20, px), __fmul_rn(F21, py)), F22);

    bool horiz  = fabsf(bv) >= fabsf(av);
    float ncoef = horiz ? av : bv;
    float den   = __fmul_rn(horiz ? bv : av, d);
    float nrec  = -__fdiv_rn(1.0f, den);   // den 0/Inf/NaN -> u NaN -> masked

    const float4* P = cubes + (size_t)b * (2 * CUBE) + (horiz ? 0 : CUBE);

    // Conservative valid-k interval, PER LANE (exact mask still applied).
    float A  = __fmul_rn(__fmul_rn(ncoef, d), nrec);
    float Bc = __fmul_rn(cv, nrec);
    int lkmin, lkmax;
    if (fabsf(A) > 1e-20f) {
        float inv = 1.0f / A;
        float k1 = (0.0f   - Bc) * inv;
        float k2 = (127.0f - Bc) * inv;
        float lo = fmaxf(fminf(k1, k2) - 2.0f, 0.0f);
        float hi = fminf(fmaxf(k1, k2) + 2.0f, 127.0f);
        if (lo > hi || !(lo == lo)) { lkmin = 1; lkmax = 0; }
        else { lkmin = (int)lo; lkmax = (int)hi; }
    } else {
        bool full = (Bc >= 0.0f) && (Bc <= 127.0f);
        lkmin = full ? 0 : 1;
        lkmax = full ? 127 : 0;
    }

    float a0 = 0.f, a1 = 0.f, a2 = 0.f, a3 = 0.f;
    int len = lkmax - lkmin + 1;          // may be <=0 (empty)
    int cnt = (len + 7) >> 3;             // steps per seg for THIS lane
    int ks  = lkmin + seg * cnt;
    int ke  = min(ks + cnt - 1, lkmax);   // empty if len<=0
    #pragma unroll 8
    for (int k = ks; k <= ke; ++k) {
        float m  = __fmul_rn((float)k, d);
        float q  = __fadd_rn(__fmul_rn(ncoef, m), cv);
        float u  = __fmul_rn(q, nrec);
        bool ok  = (u >= 0.f) && (u <= 127.f);
        int i0   = (int)floorf(u);        // NaN->0, sat; clamped next
        i0 = max(0, min(i0, 126));
        float w  = __fsub_rn(u, (float)i0);   // ==1 at u==127 -> row[127]
        h2 wp = __builtin_bit_cast(h2,
                    __builtin_amdgcn_cvt_pkrtz(__fsub_rn(1.f, w), w));
        wp = ok ? wp : (h2){(_Float16)0.f, (_Float16)0.f};
        float4 e = P[i0 * LDK + k];       // transposed [u][k] cube
        a0 = __builtin_amdgcn_fdot2(wp, __builtin_bit_cast(h2, e.x), a0, false);
        a1 = __builtin_amdgcn_fdot2(wp, __builtin_bit_cast(h2, e.y), a1, false);
        a2 = __builtin_amdgcn_fdot2(wp, __builtin_bit_cast(h2, e.z), a2, false);
        a3 = __builtin_amdgcn_fdot2(wp, __builtin_bit_cast(h2, e.w), a3, false);
    }

    __shared__ float part[8][4][64];
    part[seg][0][tx] = a0;
    part[seg][1][tx] = a1;
    part[seg][2][tx] = a2;
    part[seg][3][tx] = a3;
    __syncthreads();

    if (seg < 4) {                                // waves 0..3: one channel each
        int ch = seg;
        float s = part[0][ch][tx];
        #pragma unroll
        for (int t = 1; t < 8; ++t) s = __fadd_rn(s, part[t][ch][tx]);
        out[(((size_t)b * CC + ch) * HH + y) * WW + x] = s;
    }
}

extern "C" void kernel_launch(void* const* d_in, const int* in_sizes, int n_in,
                              void* d_out, int out_size, void* d_ws, size_t ws_size,
                              hipStream_t stream) {
    const float* view1 = (const float*)d_in[0];
    const float* F21   = (const float*)d_in[1];
    const float* dsf   = (const float*)d_in[3];

    const int B = in_sizes[3];

    dim3 stb(128, 1, 1);
    dim3 stg(HH, 2, B);
    fume_stage<<<stg, stb, 0, stream>>>(view1, (float4*)d_ws);

    dim3 ftb(64, 8, 1);
    dim3 ftg(WW / 64, HH, B);
    fume_kernel<<<ftg, ftb, 0, stream>>>((const float4*)d_ws, F21, dsf,
                                         (float*)d_out);
}